// Round 11
// baseline (628.078 us; speedup 1.0000x reference)
//
#include <hip/hip_runtime.h>

constexpr int cB  = 4;
constexpr int cN  = 1024;
constexpr int cD  = 768;
constexpr int cH  = 12;
constexpr int cHD = 64;
constexpr int cHID = 3072;
constexpr int cBN = cB * cN;   // 4096 rows

typedef __attribute__((ext_vector_type(8))) short bf16x8;
typedef __attribute__((ext_vector_type(4))) float f32x4;

static __device__ __forceinline__ unsigned short f2bf(float f) {
    union { float f; unsigned int u; } v; v.f = f;
    unsigned int u = v.u;
    return (unsigned short)((u + 0x7FFFu + ((u >> 16) & 1u)) >> 16);
}

// Exact-enough GELU: A&S 7.1.26 erf (|eps| <= 1.5e-7, branch-free, 1 exp + 1 rcp)
static __device__ __forceinline__ float gelu_as(float v) {
    float w  = v * 0.70710678118f;
    float aw = fabsf(w);
    float t  = __builtin_amdgcn_rcpf(fmaf(aw, 0.3275911f, 1.0f));
    float p  = t * fmaf(t, fmaf(t, fmaf(t, fmaf(t, 1.061405429f, -1.453152027f),
                                        1.421413741f), -0.284496736f), 0.254829592f);
    float e  = __builtin_amdgcn_exp2f(w * w * -1.44269504f);
    float ea = fmaf(-p, e, 1.0f);
    float er = __builtin_copysignf(ea, w);
    return 0.5f * v * (1.0f + er);
}

static __device__ __forceinline__ void gl_lds16(const void* g, void* l) {
    __builtin_amdgcn_global_load_lds(
        (const __attribute__((address_space(1))) unsigned int*)g,
        (__attribute__((address_space(3))) unsigned int*)l, 16, 0, 0);
}

// ---------------------------------------------------------------------------
// Batched weight convert: all 16 weight matrices in ONE launch.
// W fp32 [K][N] row-major -> bf16 B-swizzled:
//   elem(n,k) at ((n>>4)*(K/8)+(k>>3))*128 + (n&15)*8 + (k&7)
// ---------------------------------------------------------------------------
struct WcTab {
    const float* src[16];
    unsigned long long dstoff[16];
    int K[16];
    int N[16];
    int start[17];   // prefix sums of (K/64)*(N/64)
};

__global__ __launch_bounds__(256)
void wconv_all(WcTab tab, unsigned short* __restrict__ WoBase) {
    int b = blockIdx.x;
    int i = 0;
    while (i < 15 && b >= tab.start[i + 1]) i++;
    const float* __restrict__ W = tab.src[i];
    unsigned short* __restrict__ Wo = WoBase + tab.dstoff[i];
    int K = tab.K[i], N = tab.N[i];
    int tb = b - tab.start[i];
    int Kt = K >> 6;
    int k0 = (tb % Kt) * 64, n0 = (tb / Kt) * 64;

    __shared__ float Ls[64][68];
    int t = threadIdx.x;
    int lr = t >> 4, lc = (t & 15) * 4;
    #pragma unroll
    for (int q = 0; q < 4; q++) {
        float4 v = *(const float4*)&W[(size_t)(k0 + lr + q * 16) * N + n0 + lc];
        Ls[lr + q * 16][lc + 0] = v.x;  Ls[lr + q * 16][lc + 1] = v.y;
        Ls[lr + q * 16][lc + 2] = v.z;  Ls[lr + q * 16][lc + 3] = v.w;
    }
    __syncthreads();
    int mt = t >> 3;
    int nb = mt & 3, kb = mt >> 2;
    int sub = t & 7;
    int K8 = K >> 3;
    size_t chunk = ((size_t)(n0 / 16 + nb) * K8 + (size_t)(k0 / 8 + kb)) * 128;
    unsigned short buf[16];
    #pragma unroll
    for (int rr = 0; rr < 2; rr++) {
        int n_r = sub * 2 + rr;
        #pragma unroll
        for (int kk = 0; kk < 8; kk++)
            buf[rr * 8 + kk] = f2bf(Ls[kb * 8 + kk][nb * 16 + n_r]);
    }
    uint4 w0, w1;
    w0.x = buf[0] | ((unsigned)buf[1] << 16);   w0.y = buf[2] | ((unsigned)buf[3] << 16);
    w0.z = buf[4] | ((unsigned)buf[5] << 16);   w0.w = buf[6] | ((unsigned)buf[7] << 16);
    w1.x = buf[8] | ((unsigned)buf[9] << 16);   w1.y = buf[10] | ((unsigned)buf[11] << 16);
    w1.z = buf[12] | ((unsigned)buf[13] << 16); w1.w = buf[14] | ((unsigned)buf[15] << 16);
    *(uint4*)&Wo[chunk + sub * 16]     = w0;
    *(uint4*)&Wo[chunk + sub * 16 + 8] = w1;
}

// ---------------------------------------------------------------------------
// LayerNorm: fp32 in -> bf16 A-swizzled out (K=768 layout).
// ln4_kernel: up to 4 independent LN ops in one launch, 256 blocks each.
// ---------------------------------------------------------------------------
static __device__ __forceinline__ void ln_body(const float* __restrict__ x,
                                               const float* __restrict__ g,
                                               const float* __restrict__ b,
                                               unsigned short* __restrict__ y,
                                               int R) {
    __shared__ float psum[16][17], psq[16][17];
    __shared__ float mean_s[16], rstd_s[16];
    int t = threadIdx.x;
    int r = t >> 4, c16 = t & 15;
    const float* xr = x + ((size_t)R * 16 + r) * cD;
    float s = 0.f, sq = 0.f;
    #pragma unroll
    for (int i = 0; i < 12; i++) {
        float4 v = *(const float4*)&xr[c16 * 4 + i * 64];
        s  += v.x + v.y + v.z + v.w;
        sq += v.x * v.x + v.y * v.y + v.z * v.z + v.w * v.w;
    }
    psum[r][c16] = s; psq[r][c16] = sq;
    __syncthreads();
    if (t < 16) {
        float ss = 0.f, qq = 0.f;
        #pragma unroll
        for (int i = 0; i < 16; i++) { ss += psum[t][i]; qq += psq[t][i]; }
        float m = ss / (float)cD;
        mean_s[t] = m;
        rstd_s[t] = rsqrtf(qq / (float)cD - m * m + 1e-5f);
    }
    __syncthreads();
    int r2 = t & 15, cslot = t >> 4;
    const float* xr2 = x + ((size_t)R * 16 + r2) * cD;
    float m = mean_s[r2], rs = rstd_s[r2];
    for (int c = cslot; c < 96; c += 16) {
        float4 a0 = *(const float4*)&xr2[c * 8];
        float4 a1 = *(const float4*)&xr2[c * 8 + 4];
        float4 g0 = *(const float4*)&g[c * 8];
        float4 g1 = *(const float4*)&g[c * 8 + 4];
        float4 b0 = *(const float4*)&b[c * 8];
        float4 b1 = *(const float4*)&b[c * 8 + 4];
        unsigned short o[8];
        o[0] = f2bf((a0.x - m) * rs * g0.x + b0.x);
        o[1] = f2bf((a0.y - m) * rs * g0.y + b0.y);
        o[2] = f2bf((a0.z - m) * rs * g0.z + b0.z);
        o[3] = f2bf((a0.w - m) * rs * g0.w + b0.w);
        o[4] = f2bf((a1.x - m) * rs * g1.x + b1.x);
        o[5] = f2bf((a1.y - m) * rs * g1.y + b1.y);
        o[6] = f2bf((a1.z - m) * rs * g1.z + b1.z);
        o[7] = f2bf((a1.w - m) * rs * g1.w + b1.w);
        uint4 w;
        w.x = o[0] | ((unsigned)o[1] << 16); w.y = o[2] | ((unsigned)o[3] << 16);
        w.z = o[4] | ((unsigned)o[5] << 16); w.w = o[6] | ((unsigned)o[7] << 16);
        *(uint4*)&y[((size_t)R * 96 + c) * 128 + r2 * 8] = w;
    }
}

struct LnTab {
    const float* x[4];
    const float* g[4];
    const float* b[4];
    unsigned short* y[4];
};

__global__ __launch_bounds__(256)
void ln4_kernel(LnTab T) {
    int s = blockIdx.x >> 8;
    ln_body(T.x[s], T.g[s], T.b[s], T.y[s], blockIdx.x & 255);
}

// ---------------------------------------------------------------------------
// MFMA GEMM pair: grid.z in {1,2}; z selects the operand set (same shape).
// 256 threads = 4 waves, tile 128x64, 3 LDS buffers (36KB -> 4 blocks/CU).
// SINGLE-barrier pipeline (AH=1): per step {stage(s+1) -> vmcnt(3) ->
// barrier -> ds_read -> MFMA}. Safety: barrier-per-step bounds skew to one
// body; stage targets (s+1)%3 while readers touch s%3 / (s-1)%3 — distinct
// mod 3. Restage of s%3 at body s+2 is behind barrier(s+1), by which every
// wave's body-s reads are consumed (compiler lgkmcnt before MFMA use).
// vmcnt ledger: 3 loads/stage, outstanding {s,s+1}=6 -> vmcnt(3); tail 0.
// modes: 0 row-major bf16 (ostride). 1: A-swizzled + GELU. 2: fp32 + res.
//        3: split: n < vsplit -> row-major bf16 (bias); n >= vsplit -> Vt
//           (biasB[n-vsplit]).  Vt: [b*12+h][d][tok] bf16.
// ---------------------------------------------------------------------------
struct GPair {
    const unsigned short* A0;  const unsigned short* A1;
    const unsigned short* B0;  const unsigned short* B1;
    const float* bias0;        const float* bias1;
    const float* biasB0;       const float* biasB1;
    const float* res0;         const float* res1;
    void* C0;                  void* C1;
    unsigned short* V0;        unsigned short* V1;
};

__global__ __launch_bounds__(256, 4)
void mfma_gemm(GPair P, int K, int N, int ostride, int vsplit, int mode) {
    __shared__ bf16x8 aT[3][512];   // 128 rows x 32 k  (8KB / buf)
    __shared__ bf16x8 bT[3][256];   // 64 cols  x 32 k  (4KB / buf)
    int z = blockIdx.z;
    const unsigned short* A   = z ? P.A1 : P.A0;
    const unsigned short* Bw  = z ? P.B1 : P.B0;
    const float* bias  = z ? P.bias1  : P.bias0;
    const float* biasB = z ? P.biasB1 : P.biasB0;
    const float* res   = z ? P.res1   : P.res0;
    void* Cout         = z ? P.C1     : P.C0;
    unsigned short* VtOut = z ? P.V1  : P.V0;

    int t = threadIdx.x;
    int w = t >> 6, l = t & 63;
    int m0 = blockIdx.x * 128, n0 = blockIdx.y * 64;
    int K8 = K >> 3;

    f32x4 acc[2][4];
    #pragma unroll
    for (int i = 0; i < 2; i++)
        #pragma unroll
        for (int j = 0; j < 4; j++) acc[i][j] = (f32x4){0.f, 0.f, 0.f, 0.f};

    int sA0 = w * 128 + l;
    int sA1 = sA0 + 64;
    int sB  = w * 64 + l;
    int ciA0 = sA0 >> 4, ciA1 = sA1 >> 4, ciB = sB >> 4;
    const unsigned short* pA0 = A +
        ((size_t)((m0 >> 4) + (ciA0 >> 2)) * K8 + (ciA0 & 3)) * 128 + (sA0 & 15) * 8;
    const unsigned short* pA1 = A +
        ((size_t)((m0 >> 4) + (ciA1 >> 2)) * K8 + (ciA1 & 3)) * 128 + (sA1 & 15) * 8;
    const unsigned short* pB  = Bw +
        ((size_t)((n0 >> 4) + (ciB >> 2)) * K8 + (ciB & 3)) * 128 + (sB & 15) * 8;

    auto stage = [&](int buf, int step) {
        size_t off = (size_t)step * 512;
        gl_lds16(pA0 + off, &aT[buf][w * 128]);
        gl_lds16(pA1 + off, &aT[buf][w * 128 + 64]);
        gl_lds16(pB  + off, &bT[buf][w * 64]);
    };

    int nsteps = K >> 5;   // >= 24 at all call sites
    stage(0, 0);
    for (int s = 0; s < nsteps; s++) {
        int cb = s % 3;
        if (s + 1 < nsteps) {
            stage((s + 1) % 3, s + 1);
            asm volatile("s_waitcnt vmcnt(3)" ::: "memory");   // stage(s) landed
        } else {
            asm volatile("s_waitcnt vmcnt(0)" ::: "memory");
        }
        __builtin_amdgcn_s_barrier();   // all waves' staging for step s visible

        bf16x8 av[2], bv[4];
        #pragma unroll
        for (int i = 0; i < 2; i++) av[i] = aT[cb][(2 * w + i) * 64 + l];
        #pragma unroll
        for (int j = 0; j < 4; j++) bv[j] = bT[cb][j * 64 + l];
        #pragma unroll
        for (int i = 0; i < 2; i++)
            #pragma unroll
            for (int j = 0; j < 4; j++)
                acc[i][j] = __builtin_amdgcn_mfma_f32_16x16x32_bf16(av[i], bv[j], acc[i][j], 0, 0, 0);
        // no trailing barrier/lgkmcnt: reads are consumed by MFMAs before the
        // wave reaches barrier(s+1); buf cb is not restaged until body s+2.
    }

    int col = l & 15;
    int rb = (l >> 4) * 4;
    int mw = m0 + w * 32;
    if (mode == 2) {
        float* out = (float*)Cout;
        #pragma unroll
        for (int j = 0; j < 4; j++) {
            int n = n0 + j * 16 + col;
            float bj = bias[n];
            #pragma unroll
            for (int i = 0; i < 2; i++)
                #pragma unroll
                for (int r = 0; r < 4; r++) {
                    int mm = mw + i * 16 + rb + r;
                    out[(size_t)mm * ostride + n] = acc[i][j][r] + bj + res[(size_t)mm * ostride + n];
                }
        }
    } else if (mode == 1) {
        unsigned short* out = (unsigned short*)Cout;
        int N8 = N >> 3;
        #pragma unroll
        for (int j = 0; j < 4; j++) {
            int n = n0 + j * 16 + col;
            float bj = bias[n];
            #pragma unroll
            for (int i = 0; i < 2; i++)
                #pragma unroll
                for (int r = 0; r < 4; r++) {
                    int mm = mw + i * 16 + rb + r;
                    float v = gelu_as(acc[i][j][r] + bj);
                    size_t ad = ((size_t)(mm >> 4) * N8 + (n >> 3)) * 128 + (mm & 15) * 8 + (n & 7);
                    out[ad] = f2bf(v);
                }
        }
    } else {
        bool toVt = (mode == 3) && (n0 >= vsplit);
        if (!toVt) {
            unsigned short* out = (unsigned short*)Cout;
            #pragma unroll
            for (int j = 0; j < 4; j++) {
                int n = n0 + j * 16 + col;
                float bj = bias[n];
                #pragma unroll
                for (int i = 0; i < 2; i++)
                    #pragma unroll
                    for (int r = 0; r < 4; r++) {
                        int mm = mw + i * 16 + rb + r;
                        out[(size_t)mm * ostride + n] = f2bf(acc[i][j][r] + bj);
                    }
            }
        } else {
            #pragma unroll
            for (int j = 0; j < 4; j++) {
                int n = n0 + j * 16 + col;
                int vc = n - vsplit;
                float bj = biasB[vc];
                int ph = vc >> 6, d = vc & 63;
                #pragma unroll
                for (int i = 0; i < 2; i++) {
                    int mm = mw + i * 16 + rb;
                    int bbv = mm >> 10, tok = mm & 1023;
                    unsigned short q0 = f2bf(acc[i][j][0] + bj);
                    unsigned short q1 = f2bf(acc[i][j][1] + bj);
                    unsigned short q2 = f2bf(acc[i][j][2] + bj);
                    unsigned short q3 = f2bf(acc[i][j][3] + bj);
                    uint2 pk;
                    pk.x = q0 | ((unsigned)q1 << 16);
                    pk.y = q2 | ((unsigned)q3 << 16);
                    size_t ad = ((size_t)(bbv * 12 + ph) * 64 + d) * 1024 + tok;
                    *(uint2*)&VtOut[ad] = pk;
                }
            }
        }
    }
}

// ---------------------------------------------------------------------------
// MFMA flash attention (pairable via grid.z). QBLK=32: each wave owns 32
// q-rows (2 fragment sets), block covers 128 q-rows. XCD-aware block
// swizzle: all 8 q-chunks of a head share blk%8 (= same XCD under the
// round-robin dispatch) so the head's 256KB K/V slice is fetched into ONE
// XCD L2 (6 heads x 2 z = 3MB/XCD, fits 4MB) instead of all eight.
// Softmax: log2 domain, deferred max, row-sum via ones-MFMA, cvt_pk pack.
// ---------------------------------------------------------------------------
__global__ __launch_bounds__(256, 2)
void fattn_kernel(const unsigned short* __restrict__ Q0,
                  const unsigned short* __restrict__ Q1,
                  const unsigned short* __restrict__ Kq0,
                  const unsigned short* __restrict__ Kq1,
                  const unsigned short* __restrict__ Vt0,
                  const unsigned short* __restrict__ Vt1,
                  unsigned short* __restrict__ Oo0,
                  unsigned short* __restrict__ Oo1,
                  int qk_stride, float scale) {
    __shared__ unsigned short Kls[2][4096];   // [64 keys][64 dims], swizzled
    __shared__ unsigned short Vls[2][4096];   // [64 dims][64 toks], swizzled
    __shared__ unsigned short Ps[4][32][72];

    int z = blockIdx.z;
    const unsigned short* Qp = z ? Q1 : Q0;
    const unsigned short* Kp = z ? Kq1 : Kq0;
    const unsigned short* Vt = z ? Vt1 : Vt0;
    unsigned short* O        = z ? Oo1 : Oo0;

    int t = threadIdx.x;
    int w = t >> 6, l = t & 63;
    int la = l & 15, lb = l >> 4;
    int swz = la & 7;
    // XCD swizzle: blk = j*8 + xcd, j = jhi*8 + qchunk, bh = xcd*6 + jhi.
    // Bijective over 384 = 8 xcd x 6 jhi x 8 qchunk.
    int blk = blockIdx.x;
    int qt0 = ((blk >> 3) & 7) * 128 + w * 32;
    int bh = (blk & 7) * 6 + (blk >> 6);
    int h = bh % cH, bb = bh / cH;

    const unsigned short* Qb = Qp + (size_t)(bb * cN) * qk_stride + h * cHD;
    const unsigned short* Kb = Kp + (size_t)(bb * cN) * qk_stride + h * cHD;
    const unsigned short* Vb = Vt + (size_t)(bb * cH + h) * (64 * 1024);

    bf16x8 av[2][2];
    #pragma unroll
    for (int u = 0; u < 2; u++)
        #pragma unroll
        for (int s = 0; s < 2; s++)
            av[u][s] = *(const bf16x8*)(Qb + (size_t)(qt0 + u * 16 + la) * qk_stride + 32 * s + 8 * lb);

    int ch0 = w * 128 + l;
    int ch1 = ch0 + 64;
    int r0 = ch0 >> 3, c0 = (ch0 & 7) ^ (r0 & 7);
    int r1 = ch1 >> 3, c1 = (ch1 & 7) ^ (r1 & 7);
    const unsigned short* K0 = Kb + (size_t)r0 * qk_stride + c0 * 8;
    const unsigned short* K1 = Kb + (size_t)r1 * qk_stride + c1 * 8;
    const unsigned short* V0 = Vb + (size_t)r0 * 1024 + c0 * 8;
    const unsigned short* V1 = Vb + (size_t)r1 * 1024 + c1 * 8;
    int dst0 = w * 1024;
    int dst1 = dst0 + 512;

    auto stage = [&](int buf, int kt0) {
        gl_lds16(K0 + (size_t)kt0 * qk_stride, &Kls[buf][dst0]);
        gl_lds16(K1 + (size_t)kt0 * qk_stride, &Kls[buf][dst1]);
        gl_lds16(V0 + kt0, &Vls[buf][dst0]);
        gl_lds16(V1 + kt0, &Vls[buf][dst1]);
    };

    const float sc2 = scale * 1.44269504f;   // fold log2(e): p = 2^(s*sc2 - m2)
    bf16x8 ones;
    #pragma unroll
    for (int e = 0; e < 8; e++) ones[e] = (short)0x3F80;   // bf16 1.0

    float m2[2][4];
    f32x4 acc_o[2][4], acc_l[2];
    #pragma unroll
    for (int u = 0; u < 2; u++) {
        #pragma unroll
        for (int r = 0; r < 4; r++) m2[u][r] = -1e30f;
        acc_l[u] = (f32x4){0.f, 0.f, 0.f, 0.f};
        #pragma unroll
        for (int nt = 0; nt < 4; nt++) acc_o[u][nt] = (f32x4){0.f, 0.f, 0.f, 0.f};
    }

    stage(0, 0);
    for (int it = 0; it < 16; it++) {
        int cb = it & 1;
        if (it < 15) {
            stage(cb ^ 1, (it + 1) << 6);
            asm volatile("s_waitcnt vmcnt(4)" ::: "memory");   // cur tile landed
        } else {
            asm volatile("s_waitcnt vmcnt(0)" ::: "memory");
        }
        __builtin_amdgcn_s_barrier();
        asm volatile("" ::: "memory");

        // ---- K frags from LDS (shared by both q-sets)
        bf16x8 kf[4][2];
        #pragma unroll
        for (int j = 0; j < 4; j++)
            #pragma unroll
            for (int s = 0; s < 2; s++)
                kf[j][s] = *(const bf16x8*)&Kls[cb][(16 * j + la) * 64 + (((4 * s + lb) ^ swz) << 3)];

        // ---- S = Q K^T for both q-sets
        f32x4 sj[2][4];
        #pragma unroll
        for (int u = 0; u < 2; u++)
            #pragma unroll
            for (int j = 0; j < 4; j++) sj[u][j] = (f32x4){0.f, 0.f, 0.f, 0.f};
        #pragma unroll
        for (int j = 0; j < 4; j++)
            #pragma unroll
            for (int s = 0; s < 2; s++)
                #pragma unroll
                for (int u = 0; u < 2; u++)
                    sj[u][j] = __builtin_amdgcn_mfma_f32_16x16x32_bf16(av[u][s], kf[j][s], sj[u][j], 0, 0, 0);

        // ---- softmax per q-set: log2 domain, deferred max
        #pragma unroll
        for (int u = 0; u < 2; u++) {
            float x2[4][4];
            #pragma unroll
            for (int j = 0; j < 4; j++)
                #pragma unroll
                for (int r = 0; r < 4; r++) x2[j][r] = sj[u][j][r] * sc2;

            float p[4][4];
            #pragma unroll
            for (int j = 0; j < 4; j++)
                #pragma unroll
                for (int r = 0; r < 4; r++)
                    p[j][r] = __builtin_amdgcn_exp2f(x2[j][r] - m2[u][r]);

            float mt2[4];
            #pragma unroll
            for (int r = 0; r < 4; r++)
                mt2[r] = fmaxf(fmaxf(x2[0][r], x2[1][r]), fmaxf(x2[2][r], x2[3][r]));
            #pragma unroll
            for (int off = 1; off <= 8; off <<= 1)
                #pragma unroll
                for (int r = 0; r < 4; r++)
                    mt2[r] = fmaxf(mt2[r], __shfl_xor(mt2[r], off, 64));

            int ok = (mt2[0] <= m2[u][0] + 11.f) && (mt2[1] <= m2[u][1] + 11.f) &&
                     (mt2[2] <= m2[u][2] + 11.f) && (mt2[3] <= m2[u][3] + 11.f);
            if (!__all(ok)) {
                #pragma unroll
                for (int r = 0; r < 4; r++) {
                    float mn = fmaxf(m2[u][r], mt2[r]);
                    float al = __builtin_amdgcn_exp2f(m2[u][r] - mn);
                    acc_l[u][r] *= al;
                    #pragma unroll
                    for (int nt = 0; nt < 4; nt++) acc_o[u][nt][r] *= al;
                    m2[u][r] = mn;
                }
                #pragma unroll
                for (int j = 0; j < 4; j++)
                    #pragma unroll
                    for (int r = 0; r < 4; r++)
                        p[j][r] = __builtin_amdgcn_exp2f(x2[j][r] - m2[u][r]);
            }

            // P pack (cvt_pk) -> wave-private LDS rows [u*16, u*16+16)
            #pragma unroll
            for (int j = 0; j < 4; j++)
                #pragma unroll
                for (int rp = 0; rp < 2; rp++) {
                    unsigned uw;
                    asm("v_cvt_pk_bf16_f32 %0, %1, %2"
                        : "=v"(uw) : "v"(p[j][2 * rp]), "v"(p[j][2 * rp + 1]));
                    Ps[w][u * 16 + lb * 4 + 2 * rp][16 * j + la]     = (unsigned short)uw;
                    Ps[w][u * 16 + lb * 4 + 2 * rp + 1][16 * j + la] = (unsigned short)(uw >> 16);
                }
        }
        asm volatile("s_waitcnt lgkmcnt(0)" ::: "memory");
        bf16x8 pf[2][2];
        #pragma unroll
        for (int u = 0; u < 2; u++)
            #pragma unroll
            for (int s = 0; s < 2; s++)
                pf[u][s] = *(const bf16x8*)&Ps[w][u * 16 + la][32 * s + 8 * lb];

        // ---- V frags from LDS (shared), O += P V ; l += P·1
        bf16x8 vf[4][2];
        #pragma unroll
        for (int nt = 0; nt < 4; nt++)
            #pragma unroll
            for (int s = 0; s < 2; s++)
                vf[nt][s] = *(const bf16x8*)&Vls[cb][(16 * nt + la) * 64 + (((4 * s + lb) ^ swz) << 3)];
        #pragma unroll
        for (int nt = 0; nt < 4; nt++)
            #pragma unroll
            for (int s = 0; s < 2; s++)
                #pragma unroll
                for (int u = 0; u < 2; u++)
                    acc_o[u][nt] = __builtin_amdgcn_mfma_f32_16x16x32_bf16(pf[u][s], vf[nt][s], acc_o[u][nt], 0, 0, 0);
        #pragma unroll
        for (int s = 0; s < 2; s++)
            #pragma unroll
            for (int u = 0; u < 2; u++)
                acc_l[u] = __builtin_amdgcn_mfma_f32_16x16x32_bf16(pf[u][s], ones, acc_l[u], 0, 0, 0);

        // drain ds_reads so next iteration's restage of buf cb can't race them
        asm volatile("s_waitcnt lgkmcnt(0)" ::: "memory");
        __builtin_amdgcn_s_barrier();
    }

    // ---- epilogue: O/l, A-swizzled store (K=768 layout)
    #pragma unroll
    for (int u = 0; u < 2; u++) {
        float inv[4];
        #pragma unroll
        for (int r = 0; r < 4; r++) inv[r] = 1.0f / acc_l[u][r];
        size_t mhi = ((size_t)bb * cN + qt0 + u * 16) >> 4;
        #pragma unroll
        for (int nt = 0; nt < 4; nt++) {
            int k = h * cHD + 16 * nt + la;
            size_t base = (mhi * 96 + (k >> 3)) * 128 + (k & 7);
            #pragma unroll
            for (int r = 0; r < 4; r++) {
                unsigned short val = f2bf(acc_o[u][nt][r] * inv[r]);
                O[base + (lb * 4 + r) * 8] = val;
            }
        }
    }
}

// ---------------------------------------------------------------------------
extern "C" void kernel_launch(void* const* d_in, const int* in_sizes, int n_in,
                              void* d_out, int out_size, void* d_ws, size_t ws_size,
                              hipStream_t stream) {
    const float* img_tok  = (const float*)d_in[0];
    const float* evt_tok  = (const float*)d_in[1];
    const float* ln_q1_g  = (const float*)d_in[2];
    const float* ln_q1_b  = (const float*)d_in[3];
    const float* ln_kv1_g = (const float*)d_in[4];
    const float* ln_kv1_b = (const float*)d_in[5];
    const float* ln_q2_g  = (const float*)d_in[6];
    const float* ln_q2_b  = (const float*)d_in[7];
    const float* ln_kv2_g = (const float*)d_in[8];
    const float* ln_kv2_b = (const float*)d_in[9];
    const float* ln_mi_g  = (const float*)d_in[10];
    const float* ln_mi_b  = (const float*)d_in[11];
    const float* ln_me_g  = (const float*)d_in[12];
    const float* ln_me_b  = (const float*)d_in[13];
    const float* si_qkv_w  = (const float*)d_in[14];
    const float* si_qkv_b  = (const float*)d_in[15];
    const float* si_proj_w = (const float*)d_in[16];
    const float* si_proj_b = (const float*)d_in[17];
    const float* se_qkv_w  = (const float*)d_in[18];
    const float* se_qkv_b  = (const float*)d_in[19];
    const float* se_proj_w = (const float*)d_in[20];
    const float* se_proj_b = (const float*)d_in[21];
    const float* xei_q_w = (const float*)d_in[22];
    const float* xei_q_b = (const float*)d_in[23];
    const float* xei_k_w = (const float*)d_in[24];
    const float* xei_k_b = (const float*)d_in[25];
    const float* xei_v_w = (const float*)d_in[26];
    const float* xei_v_b = (const float*)d_in[27];
    const float* xei_p_w = (const float*)d_in[28];
    const float* xei_p_b = (const float*)d_in[29];
    const float* xie_q_w = (const float*)d_in[30];
    const float* xie_q_b = (const float*)d_in[31];
    const float* xie_k_w = (const float*)d_in[32];
    const float* xie_k_b = (const float*)d_in[33];
    const float* xie_v_w = (const float*)d_in[34];
    const float* xie_v_b = (const float*)d_in[35];
    const float* xie_p_w = (const float*)d_in[36];
    const float* xie_p_b = (const float*)d_in[37];
    const float* mi_fc1_w = (const float*)d_in[38];
    const float* mi_fc1_b = (const float*)d_in[39];
    const float* mi_fc2_w = (const float*)d_in[40];
    const float* mi_fc2_b = (const float*)d_in[41];
    const float* me_fc1_w = (const float*)d_in[42];
    const float* me_fc1_b = (const float*)d_in[43];
    const float* me_fc2_w = (const float*)d_in[44];
    const float* me_fc2_b = (const float*)d_in[45];

    const size_t U = (size_t)cBN * cD;               // 3,145,728
    unsigned short* wsb = (unsigned short*)d_ws;
    unsigned short* Wz  = wsb;                       // 18,874,368 elems
    unsigned short* LNo = wsb + 18874368;            // U
    unsigned short* AO  = LNo + U;                   // U
    unsigned short* T1  = AO + U;                    // 3U (row stride 2304)
    unsigned short* Vt  = T1 + 3 * U;                // U  [48][64][1024]
    // extended region (batched path only): second QKV set + second hidden
    unsigned short* T1b  = Vt + U;                   // 3U
    unsigned short* Vtb  = T1b + 3 * U;              // U
    unsigned short* Hidb = Vtb + U;                  // 4U
    float* out_img = (float*)d_out;
    float* out_evt = out_img + U;

    const bool big = ws_size >= (size_t)(18874368 + 14 * U) * 2;

    // weight offsets (bf16 elems); 768x768 = 589824
    const size_t O_SI_QKV = 0,        O_SE_QKV = 1769472;
    const size_t O_SI_P   = 3538944,  O_SE_P   = 4128768;
    const size_t O_XEI_Q  = 4718592,  O_XEI_KV = 5308416, O_XEI_P = 6488064;
    const size_t O_XIE_Q  = 7077888,  O_XIE_KV = 7667712, O_XIE_P = 8847360;
    const size_t O_MI_F1  = 9437184,  O_MI_F2  = 11796480;
    const size_t O_ME_F1  = 14155776, O_ME_F2  = 16515072;

    // ---- batched weight conversion (one launch)
    {
        WcTab tab;
        const float* srcs[16] = { si_qkv_w, se_qkv_w, si_proj_w, se_proj_w,
                                  xei_q_w, xei_k_w, xei_v_w, xei_p_w,
                                  xie_q_w, xie_k_w, xie_v_w, xie_p_w,
                                  mi_fc1_w, mi_fc2_w, me_fc1_w, me_fc2_w };
        const size_t offs[16] = { O_SI_QKV, O_SE_QKV, O_SI_P, O_SE_P,
                                  O_XEI_Q, O_XEI_KV, O_XEI_KV + 589824, O_XEI_P,
                                  O_XIE_Q, O_XIE_KV, O_XIE_KV + 589824, O_XIE_P,
                                  O_MI_F1, O_MI_F2, O_ME_F1, O_ME_F2 };
        const int Ks[16] = { 768, 768, 768, 768, 768, 768, 768, 768,
                             768, 768, 768, 768, 768, 3072, 768, 3072 };
        const int Ns[16] = { 2304, 2304, 768, 768, 768, 768, 768, 768,
                             768, 768, 768, 768, 3072, 768, 3072, 768 };
        int acc = 0;
        for (int i = 0; i < 16; i++) {
            tab.src[i] = srcs[i];
            tab.dstoff[i] = offs[i];
            tab.K[i] = Ks[i];
            tab.N[i] = Ns[i];
            tab.start[i] = acc;
            acc += (Ks[i] / 64) * (Ns[i] / 64);
        }
        tab.start[16] = acc;   // 4608
        hipLaunchKernelGGL(wconv_all, dim3(acc), dim3(256), 0, stream, tab, Wz);
    }

    const float SC = 0.125f;

    // helpers ---------------------------------------------------------------
    auto lnN = [&](int nsets, const float* x0, const float* g0, const float* b0, unsigned short* y0,
                   const float* x1, const float* g1, const float* b1, unsigned short* y1,
                   const float* x2, const float* g2, const float* b2, unsigned short* y2,
                   const float* x3, const float* g3, const float* b3, unsigned short* y3) {
        LnTab T = {{x0, x1, x2, x3}, {g0, g1, g2, g3}, {b0, b1, b2, b3}, {y0, y1, y2, y3}};
        hipLaunchKernelGGL(ln4_kernel, dim3(nsets * 256), dim3(256), 0, stream, T);
    };
    auto gemm2 = [&](dim3 grid, GPair P, int K_, int N_, int ostride_, int vsplit_, int mode_) {
        hipLaunchKernelGGL(mfma_gemm, grid, dim3(256), 0, stream, P, K_, N_, ostride_, vsplit_, mode_);
    };
    auto attn2 = [&](int nz, const unsigned short* q0, const unsigned short* k0, const unsigned short* v0, unsigned short* o0,
                     const unsigned short* q1, const unsigned short* k1, const unsigned short* v1, unsigned short* o1,
                     float sc) {
        hipLaunchKernelGGL(fattn_kernel, dim3(cB * cH * 8, 1, nz), dim3(256), 0, stream,
                           q0, q1, k0, k1, v0, v1, o0, o1, 2304, sc);
    };

    if (big) {
        // ================= batched pair schedule =================
        // 1) LN(q1 img)->LNo, LN(kv1 evt)->AO
        lnN(2, img_tok, ln_q1_g, ln_q1_b, LNo,  evt_tok, ln_kv1_g, ln_kv1_b, AO,
               img_tok, ln_q1_g, ln_q1_b, LNo,  img_tok, ln_q1_g, ln_q1_b, LNo);
        // 2) qkv pair: si->T1/Vt, se->T1b/Vtb
        gemm2(dim3(32, 36, 2),
              {LNo, AO, Wz + O_SI_QKV, Wz + O_SE_QKV, si_qkv_b, se_qkv_b,
               si_qkv_b + 1536, se_qkv_b + 1536, nullptr, nullptr, T1, T1b, Vt, Vtb},
              768, 2304, 2304, 1536, 3);
        // 3) attn pair: si->LNo, se->AO
        attn2(2, T1, T1 + 768, Vt, LNo,  T1b, T1b + 768, Vtb, AO, SC);
        // 4) proj pair -> out_img/out_evt (i1/e1)
        gemm2(dim3(32, 12, 2),
              {LNo, AO, Wz + O_SI_P, Wz + O_SE_P, si_proj_b, se_proj_b,
               nullptr, nullptr, img_tok, evt_tok, out_img, out_evt, nullptr, nullptr},
              768, 768, 768, 0, 2);
        // 5) 4 cross LNs: q2(i1)->LNo, kv2(e1)->AO, kv2(i1)->Hidb0, q2(e1)->Hidb1
        lnN(4, out_img, ln_q2_g, ln_q2_b, LNo,   out_evt, ln_kv2_g, ln_kv2_b, AO,
               out_img, ln_kv2_g, ln_kv2_b, Hidb, out_evt, ln_q2_g, ln_q2_b, Hidb + U);
        // 6) q pair: xei_q(LNo)->T1, xie_q(Hidb1)->T1b
        gemm2(dim3(32, 12, 2),
              {LNo, Hidb + U, Wz + O_XEI_Q, Wz + O_XIE_Q, xei_q_b, xie_q_b,
               nullptr, nullptr, nullptr, nullptr, T1, T1b, nullptr, nullptr},
              768, 768, 2304, 1 << 30, 0);
        // 7) kv pair: xei_kv(AO)->T1+768/Vt, xie_kv(Hidb0)->T1b+768/Vtb
        gemm2(dim3(32, 24, 2),
              {AO, Hidb, Wz + O_XEI_KV, Wz + O_XIE_KV, xei_k_b, xie_k_b,
               xei_v_b, xie_v_b, nullptr, nullptr, T1 + 768, T1b + 768, Vt, Vtb},
              768, 1536, 2304, 768, 3);
        // 8) attn pair (negated): xei->LNo, xie->AO
        attn2(2, T1, T1 + 768, Vt, LNo,  T1b, T1b + 768, Vtb, AO, -SC);
        // 9) P pair -> i2/e2
        gemm2(dim3(32, 12, 2),
              {LNo, AO, Wz + O_XEI_P, Wz + O_XIE_P, xei_p_b, xie_p_b,
               nullptr, nullptr, out_img, out_evt, out_img, out_evt, nullptr, nullptr},
              768, 768, 768, 0, 2);
        // 10) MLP LNs: mi->LNo, me->AO
        lnN(2, out_img, ln_mi_g, ln_mi_b, LNo,  out_evt, ln_me_g, ln_me_b, AO,
               out_img, ln_mi_g, ln_mi_b, LNo,  out_img, ln_mi_g, ln_mi_b, LNo);
        // 11) fc1 pair: mi->Hid_mi(=T1..Vt 4U), me->Hidb
        gemm2(dim3(32, 48, 2),
              {LNo, AO, Wz + O_MI_F1, Wz + O_ME_F1, mi_fc1_b, me_fc1_b,
               nullptr, nullptr, nullptr, nullptr, T1, Hidb, nullptr, nullptr},
              768, 3072, 3072, 0, 1);
        // 12) fc2 pair -> final outputs
        gemm2(dim3(32, 12, 2),
              {T1, Hidb, Wz + O_MI_F2, Wz + O_ME_F2, mi_fc2_b, me_fc2_b,
               nullptr, nullptr, out_img, out_evt, out_img, out_evt, nullptr, nullptr},
              3072, 768, 768, 0, 2);
    } else {
        // ================= fallback: round-4 sequential schedule =================
        unsigned short* Hid = AO;   // 4U alias (AO + T1)
        auto ln1 = [&](const float* x_, const float* g_, const float* b_, unsigned short* y_) {
            lnN(1, x_, g_, b_, y_, x_, g_, b_, y_, x_, g_, b_, y_, x_, g_, b_, y_);
        };
        auto gemm1 = [&](const unsigned short* A_, size_t woff, const float* b_, const float* bB_,
                         const float* r_, void* C_, unsigned short* V_, int K_, int N_,
                         int ostride_, int vsplit_, int mode_) {
            gemm2(dim3(cBN / 128, N_ / 64, 1),
                  {A_, A_, Wz + woff, Wz + woff, b_, b_, bB_, bB_, r_, r_, C_, C_, V_, V_},
                  K_, N_, ostride_, vsplit_, mode_);
        };
        auto attn1 = [&](const unsigned short* q_, const unsigned short* k_,
                         unsigned short* o_, float sc_) {
            attn2(1, q_, k_, Vt, o_, q_, k_, Vt, o_, sc_);
        };

        ln1(img_tok, ln_q1_g, ln_q1_b, LNo);
        gemm1(LNo, O_SI_QKV, si_qkv_b, si_qkv_b + 1536, nullptr, T1, Vt, 768, 2304, 2304, 1536, 3);
        attn1(T1, T1 + 768, AO, SC);
        gemm1(AO, O_SI_P, si_proj_b, nullptr, img_tok, out_img, Vt, 768, 768, 768, 0, 2);

        ln1(evt_tok, ln_kv1_g, ln_kv1_b, LNo);
        gemm1(LNo, O_SE_QKV, se_qkv_b, se_qkv_b + 1536, nullptr, T1, Vt, 768, 2304, 2304, 1536, 3);
        attn1(T1, T1 + 768, AO, SC);
        gemm1(AO, O_SE_P, se_proj_b, nullptr, evt_tok, out_evt, Vt, 768, 768, 768, 0, 2);

        ln1(out_img, ln_q2_g, ln_q2_b, LNo);
        gemm1(LNo, O_XEI_Q, xei_q_b, nullptr, nullptr, T1, Vt, 768, 768, 2304, 1 << 30, 0);
        ln1(out_evt, ln_kv2_g, ln_kv2_b, LNo);
        gemm1(LNo, O_XEI_KV, xei_k_b, xei_v_b, nullptr, T1 + 768, Vt, 768, 1536, 2304, 768, 3);
        attn1(T1, T1 + 768, AO, -SC);

        ln1(out_img, ln_kv2_g, ln_kv2_b, LNo);
        gemm1(LNo, O_XIE_KV, xie_k_b, xie_v_b, nullptr, T1 + 768, Vt, 768, 1536, 2304, 768, 3);
        ln1(out_evt, ln_q2_g, ln_q2_b, LNo);
        gemm1(LNo, O_XIE_Q, xie_q_b, nullptr, nullptr, T1, Vt, 768, 768, 2304, 1 << 30, 0);

        gemm1(AO, O_XEI_P, xei_p_b, nullptr, out_img, out_img, Vt, 768, 768, 768, 0, 2);
        attn1(T1, T1 + 768, AO, -SC);
        gemm1(AO, O_XIE_P, xie_p_b, nullptr, out_evt, out_evt, Vt, 768, 768, 768, 0, 2);

        lnN(2, out_img, ln_mi_g, ln_mi_b, LNo,  out_evt, ln_me_g, ln_me_b, Vt,
               out_img, ln_mi_g, ln_mi_b, LNo,  out_img, ln_mi_g, ln_mi_b, LNo);
        gemm1(LNo, O_MI_F1, mi_fc1_b, nullptr, nullptr, Hid, Vt, 768, 3072, 3072, 0, 1);
        gemm1(Hid, O_MI_F2, mi_fc2_b, nullptr, out_img, out_img, Vt, 3072, 768, 768, 0, 2);
        gemm1(Vt,  O_ME_F1, me_fc1_b, nullptr, nullptr, Hid, Vt, 768, 3072, 3072, 0, 1);
        gemm1(Hid, O_ME_F2, me_fc2_b, nullptr, out_evt, out_evt, Vt, 3072, 768, 768, 0, 2);
    }
}

// Round 13
// 617.423 us; speedup vs baseline: 1.0173x; 1.0173x over previous
//
#include <hip/hip_runtime.h>

constexpr int cB  = 4;
constexpr int cN  = 1024;
constexpr int cD  = 768;
constexpr int cH  = 12;
constexpr int cHD = 64;
constexpr int cHID = 3072;
constexpr int cBN = cB * cN;   // 4096 rows

typedef __attribute__((ext_vector_type(8))) short bf16x8;
typedef __attribute__((ext_vector_type(4))) float f32x4;

static __device__ __forceinline__ unsigned short f2bf(float f) {
    union { float f; unsigned int u; } v; v.f = f;
    unsigned int u = v.u;
    return (unsigned short)((u + 0x7FFFu + ((u >> 16) & 1u)) >> 16);
}

// Exact-enough GELU: A&S 7.1.26 erf (|eps| <= 1.5e-7, branch-free, 1 exp + 1 rcp)
static __device__ __forceinline__ float gelu_as(float v) {
    float w  = v * 0.70710678118f;
    float aw = fabsf(w);
    float t  = __builtin_amdgcn_rcpf(fmaf(aw, 0.3275911f, 1.0f));
    float p  = t * fmaf(t, fmaf(t, fmaf(t, fmaf(t, 1.061405429f, -1.453152027f),
                                        1.421413741f), -0.284496736f), 0.254829592f);
    float e  = __builtin_amdgcn_exp2f(w * w * -1.44269504f);
    float ea = fmaf(-p, e, 1.0f);
    float er = __builtin_copysignf(ea, w);
    return 0.5f * v * (1.0f + er);
}

static __device__ __forceinline__ void gl_lds16(const void* g, void* l) {
    __builtin_amdgcn_global_load_lds(
        (const __attribute__((address_space(1))) unsigned int*)g,
        (__attribute__((address_space(3))) unsigned int*)l, 16, 0, 0);
}

// ---------------------------------------------------------------------------
// Batched weight convert: all 16 weight matrices in ONE launch.
// W fp32 [K][N] row-major -> bf16 B-swizzled:
//   elem(n,k) at ((n>>4)*(K/8)+(k>>3))*128 + (n&15)*8 + (k&7)
// ---------------------------------------------------------------------------
struct WcTab {
    const float* src[16];
    unsigned long long dstoff[16];
    int K[16];
    int N[16];
    int start[17];   // prefix sums of (K/64)*(N/64)
};

__global__ __launch_bounds__(256)
void wconv_all(WcTab tab, unsigned short* __restrict__ WoBase) {
    int b = blockIdx.x;
    int i = 0;
    while (i < 15 && b >= tab.start[i + 1]) i++;
    const float* __restrict__ W = tab.src[i];
    unsigned short* __restrict__ Wo = WoBase + tab.dstoff[i];
    int K = tab.K[i], N = tab.N[i];
    int tb = b - tab.start[i];
    int Kt = K >> 6;
    int k0 = (tb % Kt) * 64, n0 = (tb / Kt) * 64;

    __shared__ float Ls[64][68];
    int t = threadIdx.x;
    int lr = t >> 4, lc = (t & 15) * 4;
    #pragma unroll
    for (int q = 0; q < 4; q++) {
        float4 v = *(const float4*)&W[(size_t)(k0 + lr + q * 16) * N + n0 + lc];
        Ls[lr + q * 16][lc + 0] = v.x;  Ls[lr + q * 16][lc + 1] = v.y;
        Ls[lr + q * 16][lc + 2] = v.z;  Ls[lr + q * 16][lc + 3] = v.w;
    }
    __syncthreads();
    int mt = t >> 3;
    int nb = mt & 3, kb = mt >> 2;
    int sub = t & 7;
    int K8 = K >> 3;
    size_t chunk = ((size_t)(n0 / 16 + nb) * K8 + (size_t)(k0 / 8 + kb)) * 128;
    unsigned short buf[16];
    #pragma unroll
    for (int rr = 0; rr < 2; rr++) {
        int n_r = sub * 2 + rr;
        #pragma unroll
        for (int kk = 0; kk < 8; kk++)
            buf[rr * 8 + kk] = f2bf(Ls[kb * 8 + kk][nb * 16 + n_r]);
    }
    uint4 w0, w1;
    w0.x = buf[0] | ((unsigned)buf[1] << 16);   w0.y = buf[2] | ((unsigned)buf[3] << 16);
    w0.z = buf[4] | ((unsigned)buf[5] << 16);   w0.w = buf[6] | ((unsigned)buf[7] << 16);
    w1.x = buf[8] | ((unsigned)buf[9] << 16);   w1.y = buf[10] | ((unsigned)buf[11] << 16);
    w1.z = buf[12] | ((unsigned)buf[13] << 16); w1.w = buf[14] | ((unsigned)buf[15] << 16);
    *(uint4*)&Wo[chunk + sub * 16]     = w0;
    *(uint4*)&Wo[chunk + sub * 16 + 8] = w1;
}

// ---------------------------------------------------------------------------
// LayerNorm: fp32 in -> bf16 A-swizzled out (K=768 layout).
// ln4_kernel: up to 4 independent LN ops in one launch, 256 blocks each.
// ---------------------------------------------------------------------------
static __device__ __forceinline__ void ln_body(const float* __restrict__ x,
                                               const float* __restrict__ g,
                                               const float* __restrict__ b,
                                               unsigned short* __restrict__ y,
                                               int R) {
    __shared__ float psum[16][17], psq[16][17];
    __shared__ float mean_s[16], rstd_s[16];
    int t = threadIdx.x;
    int r = t >> 4, c16 = t & 15;
    const float* xr = x + ((size_t)R * 16 + r) * cD;
    float s = 0.f, sq = 0.f;
    #pragma unroll
    for (int i = 0; i < 12; i++) {
        float4 v = *(const float4*)&xr[c16 * 4 + i * 64];
        s  += v.x + v.y + v.z + v.w;
        sq += v.x * v.x + v.y * v.y + v.z * v.z + v.w * v.w;
    }
    psum[r][c16] = s; psq[r][c16] = sq;
    __syncthreads();
    if (t < 16) {
        float ss = 0.f, qq = 0.f;
        #pragma unroll
        for (int i = 0; i < 16; i++) { ss += psum[t][i]; qq += psq[t][i]; }
        float m = ss / (float)cD;
        mean_s[t] = m;
        rstd_s[t] = rsqrtf(qq / (float)cD - m * m + 1e-5f);
    }
    __syncthreads();
    int r2 = t & 15, cslot = t >> 4;
    const float* xr2 = x + ((size_t)R * 16 + r2) * cD;
    float m = mean_s[r2], rs = rstd_s[r2];
    for (int c = cslot; c < 96; c += 16) {
        float4 a0 = *(const float4*)&xr2[c * 8];
        float4 a1 = *(const float4*)&xr2[c * 8 + 4];
        float4 g0 = *(const float4*)&g[c * 8];
        float4 g1 = *(const float4*)&g[c * 8 + 4];
        float4 b0 = *(const float4*)&b[c * 8];
        float4 b1 = *(const float4*)&b[c * 8 + 4];
        unsigned short o[8];
        o[0] = f2bf((a0.x - m) * rs * g0.x + b0.x);
        o[1] = f2bf((a0.y - m) * rs * g0.y + b0.y);
        o[2] = f2bf((a0.z - m) * rs * g0.z + b0.z);
        o[3] = f2bf((a0.w - m) * rs * g0.w + b0.w);
        o[4] = f2bf((a1.x - m) * rs * g1.x + b1.x);
        o[5] = f2bf((a1.y - m) * rs * g1.y + b1.y);
        o[6] = f2bf((a1.z - m) * rs * g1.z + b1.z);
        o[7] = f2bf((a1.w - m) * rs * g1.w + b1.w);
        uint4 w;
        w.x = o[0] | ((unsigned)o[1] << 16); w.y = o[2] | ((unsigned)o[3] << 16);
        w.z = o[4] | ((unsigned)o[5] << 16); w.w = o[6] | ((unsigned)o[7] << 16);
        *(uint4*)&y[((size_t)R * 96 + c) * 128 + r2 * 8] = w;
    }
}

struct LnTab {
    const float* x[4];
    const float* g[4];
    const float* b[4];
    unsigned short* y[4];
};

__global__ __launch_bounds__(256)
void ln4_kernel(LnTab T) {
    int s = blockIdx.x >> 8;
    ln_body(T.x[s], T.g[s], T.b[s], T.y[s], blockIdx.x & 255);
}

// ---------------------------------------------------------------------------
// MFMA GEMM pair: grid.z in {1,2}; z selects the operand set (same shape).
// 256 threads = 4 waves, tile 128x64, 3 LDS buffers (36KB -> 4 blocks/CU).
// SINGLE-barrier pipeline (AH=1): per step {stage(s+1) -> vmcnt(3) ->
// barrier -> ds_read -> MFMA}.
// modes: 0 row-major bf16 (ostride). 1: A-swizzled + GELU. 2: fp32 + res.
//        3: split: n < vsplit -> row-major bf16 (bias); n >= vsplit -> Vt
//           (biasB[n-vsplit]).  Vt: [b*12+h][d][tok] bf16.
// ---------------------------------------------------------------------------
struct GPair {
    const unsigned short* A0;  const unsigned short* A1;
    const unsigned short* B0;  const unsigned short* B1;
    const float* bias0;        const float* bias1;
    const float* biasB0;       const float* biasB1;
    const float* res0;         const float* res1;
    void* C0;                  void* C1;
    unsigned short* V0;        unsigned short* V1;
};

__global__ __launch_bounds__(256, 4)
void mfma_gemm(GPair P, int K, int N, int ostride, int vsplit, int mode) {
    __shared__ bf16x8 aT[3][512];   // 128 rows x 32 k  (8KB / buf)
    __shared__ bf16x8 bT[3][256];   // 64 cols  x 32 k  (4KB / buf)
    int z = blockIdx.z;
    const unsigned short* A   = z ? P.A1 : P.A0;
    const unsigned short* Bw  = z ? P.B1 : P.B0;
    const float* bias  = z ? P.bias1  : P.bias0;
    const float* biasB = z ? P.biasB1 : P.biasB0;
    const float* res   = z ? P.res1   : P.res0;
    void* Cout         = z ? P.C1     : P.C0;
    unsigned short* VtOut = z ? P.V1  : P.V0;

    int t = threadIdx.x;
    int w = t >> 6, l = t & 63;
    int m0 = blockIdx.x * 128, n0 = blockIdx.y * 64;
    int K8 = K >> 3;

    f32x4 acc[2][4];
    #pragma unroll
    for (int i = 0; i < 2; i++)
        #pragma unroll
        for (int j = 0; j < 4; j++) acc[i][j] = (f32x4){0.f, 0.f, 0.f, 0.f};

    int sA0 = w * 128 + l;
    int sA1 = sA0 + 64;
    int sB  = w * 64 + l;
    int ciA0 = sA0 >> 4, ciA1 = sA1 >> 4, ciB = sB >> 4;
    const unsigned short* pA0 = A +
        ((size_t)((m0 >> 4) + (ciA0 >> 2)) * K8 + (ciA0 & 3)) * 128 + (sA0 & 15) * 8;
    const unsigned short* pA1 = A +
        ((size_t)((m0 >> 4) + (ciA1 >> 2)) * K8 + (ciA1 & 3)) * 128 + (sA1 & 15) * 8;
    const unsigned short* pB  = Bw +
        ((size_t)((n0 >> 4) + (ciB >> 2)) * K8 + (ciB & 3)) * 128 + (sB & 15) * 8;

    auto stage = [&](int buf, int step) {
        size_t off = (size_t)step * 512;
        gl_lds16(pA0 + off, &aT[buf][w * 128]);
        gl_lds16(pA1 + off, &aT[buf][w * 128 + 64]);
        gl_lds16(pB  + off, &bT[buf][w * 64]);
    };

    int nsteps = K >> 5;   // >= 24 at all call sites
    stage(0, 0);
    for (int s = 0; s < nsteps; s++) {
        int cb = s % 3;
        if (s + 1 < nsteps) {
            stage((s + 1) % 3, s + 1);
            asm volatile("s_waitcnt vmcnt(3)" ::: "memory");   // stage(s) landed
        } else {
            asm volatile("s_waitcnt vmcnt(0)" ::: "memory");
        }
        __builtin_amdgcn_s_barrier();   // all waves' staging for step s visible

        bf16x8 av[2], bv[4];
        #pragma unroll
        for (int i = 0; i < 2; i++) av[i] = aT[cb][(2 * w + i) * 64 + l];
        #pragma unroll
        for (int j = 0; j < 4; j++) bv[j] = bT[cb][j * 64 + l];
        #pragma unroll
        for (int i = 0; i < 2; i++)
            #pragma unroll
            for (int j = 0; j < 4; j++)
                acc[i][j] = __builtin_amdgcn_mfma_f32_16x16x32_bf16(av[i], bv[j], acc[i][j], 0, 0, 0);
        // no trailing barrier/lgkmcnt: reads are consumed by MFMAs before the
        // wave reaches barrier(s+1); buf cb is not restaged until body s+2.
    }

    int col = l & 15;
    int rb = (l >> 4) * 4;
    int mw = m0 + w * 32;
    if (mode == 2) {
        float* out = (float*)Cout;
        #pragma unroll
        for (int j = 0; j < 4; j++) {
            int n = n0 + j * 16 + col;
            float bj = bias[n];
            #pragma unroll
            for (int i = 0; i < 2; i++)
                #pragma unroll
                for (int r = 0; r < 4; r++) {
                    int mm = mw + i * 16 + rb + r;
                    out[(size_t)mm * ostride + n] = acc[i][j][r] + bj + res[(size_t)mm * ostride + n];
                }
        }
    } else if (mode == 1) {
        unsigned short* out = (unsigned short*)Cout;
        int N8 = N >> 3;
        #pragma unroll
        for (int j = 0; j < 4; j++) {
            int n = n0 + j * 16 + col;
            float bj = bias[n];
            #pragma unroll
            for (int i = 0; i < 2; i++)
                #pragma unroll
                for (int r = 0; r < 4; r++) {
                    int mm = mw + i * 16 + rb + r;
                    float v = gelu_as(acc[i][j][r] + bj);
                    size_t ad = ((size_t)(mm >> 4) * N8 + (n >> 3)) * 128 + (mm & 15) * 8 + (n & 7);
                    out[ad] = f2bf(v);
                }
        }
    } else {
        bool toVt = (mode == 3) && (n0 >= vsplit);
        if (!toVt) {
            unsigned short* out = (unsigned short*)Cout;
            #pragma unroll
            for (int j = 0; j < 4; j++) {
                int n = n0 + j * 16 + col;
                float bj = bias[n];
                #pragma unroll
                for (int i = 0; i < 2; i++)
                    #pragma unroll
                    for (int r = 0; r < 4; r++) {
                        int mm = mw + i * 16 + rb + r;
                        out[(size_t)mm * ostride + n] = f2bf(acc[i][j][r] + bj);
                    }
            }
        } else {
            #pragma unroll
            for (int j = 0; j < 4; j++) {
                int n = n0 + j * 16 + col;
                int vc = n - vsplit;
                float bj = biasB[vc];
                int ph = vc >> 6, d = vc & 63;
                #pragma unroll
                for (int i = 0; i < 2; i++) {
                    int mm = mw + i * 16 + rb;
                    int bbv = mm >> 10, tok = mm & 1023;
                    unsigned short q0 = f2bf(acc[i][j][0] + bj);
                    unsigned short q1 = f2bf(acc[i][j][1] + bj);
                    unsigned short q2 = f2bf(acc[i][j][2] + bj);
                    unsigned short q3 = f2bf(acc[i][j][3] + bj);
                    uint2 pk;
                    pk.x = q0 | ((unsigned)q1 << 16);
                    pk.y = q2 | ((unsigned)q3 << 16);
                    size_t ad = ((size_t)(bbv * 12 + ph) * 64 + d) * 1024 + tok;
                    *(uint2*)&VtOut[ad] = pk;
                }
            }
        }
    }
}

// ---------------------------------------------------------------------------
// MFMA flash attention (pairable via grid.z). QBLK=32: each wave owns 32
// q-rows, block covers 128 q-rows. XCD-aware block swizzle keeps each head's
// K/V in ONE XCD L2 (FETCH 104->18.5MB measured). Softmax: round-11 exact
// form (log2 domain, per-u deferred max with speculative exp2), row-sum via
// ones-MFMA, v_cvt_pk_bf16_f32 pack. s_setprio around MFMA clusters (T5).
// ---------------------------------------------------------------------------
__global__ __launch_bounds__(256, 2)
void fattn_kernel(const unsigned short* __restrict__ Q0,
                  const unsigned short* __restrict__ Q1,
                  const unsigned short* __restrict__ Kq0,
                  const unsigned short* __restrict__ Kq1,
                  const unsigned short* __restrict__ Vt0,
                  const unsigned short* __restrict__ Vt1,
                  unsigned short* __restrict__ Oo0,
                  unsigned short* __restrict__ Oo1,
                  int qk_stride, float scale) {
    __shared__ unsigned short Kls[2][4096];   // [64 keys][64 dims], swizzled
    __shared__ unsigned short Vls[2][4096];   // [64 dims][64 toks], swizzled
    __shared__ unsigned short Ps[4][32][72];

    int z = blockIdx.z;
    const unsigned short* Qp = z ? Q1 : Q0;
    const unsigned short* Kp = z ? Kq1 : Kq0;
    const unsigned short* Vt = z ? Vt1 : Vt0;
    unsigned short* O        = z ? Oo1 : Oo0;

    int t = threadIdx.x;
    int w = t >> 6, l = t & 63;
    int la = l & 15, lb = l >> 4;
    int swz = la & 7;
    // XCD swizzle: blk = j*8 + xcd, j = jhi*8 + qchunk, bh = xcd*6 + jhi.
    // Bijective over 384 = 8 xcd x 6 jhi x 8 qchunk.
    int blk = blockIdx.x;
    int qt0 = ((blk >> 3) & 7) * 128 + w * 32;
    int bh = (blk & 7) * 6 + (blk >> 6);
    int h = bh % cH, bb = bh / cH;

    const unsigned short* Qb = Qp + (size_t)(bb * cN) * qk_stride + h * cHD;
    const unsigned short* Kb = Kp + (size_t)(bb * cN) * qk_stride + h * cHD;
    const unsigned short* Vb = Vt + (size_t)(bb * cH + h) * (64 * 1024);

    bf16x8 av[2][2];
    #pragma unroll
    for (int u = 0; u < 2; u++)
        #pragma unroll
        for (int s = 0; s < 2; s++)
            av[u][s] = *(const bf16x8*)(Qb + (size_t)(qt0 + u * 16 + la) * qk_stride + 32 * s + 8 * lb);

    int ch0 = w * 128 + l;
    int ch1 = ch0 + 64;
    int r0 = ch0 >> 3, c0 = (ch0 & 7) ^ (r0 & 7);
    int r1 = ch1 >> 3, c1 = (ch1 & 7) ^ (r1 & 7);
    const unsigned short* K0 = Kb + (size_t)r0 * qk_stride + c0 * 8;
    const unsigned short* K1 = Kb + (size_t)r1 * qk_stride + c1 * 8;
    const unsigned short* V0 = Vb + (size_t)r0 * 1024 + c0 * 8;
    const unsigned short* V1 = Vb + (size_t)r1 * 1024 + c1 * 8;
    int dst0 = w * 1024;
    int dst1 = dst0 + 512;

    auto stage = [&](int buf, int kt0) {
        gl_lds16(K0 + (size_t)kt0 * qk_stride, &Kls[buf][dst0]);
        gl_lds16(K1 + (size_t)kt0 * qk_stride, &Kls[buf][dst1]);
        gl_lds16(V0 + kt0, &Vls[buf][dst0]);
        gl_lds16(V1 + kt0, &Vls[buf][dst1]);
    };

    const float sc2 = scale * 1.44269504f;   // fold log2(e): p = 2^(s*sc2 - m2)
    bf16x8 ones;
    #pragma unroll
    for (int e = 0; e < 8; e++) ones[e] = (short)0x3F80;   // bf16 1.0

    float m2[2][4];
    f32x4 acc_o[2][4], acc_l[2];
    #pragma unroll
    for (int u = 0; u < 2; u++) {
        #pragma unroll
        for (int r = 0; r < 4; r++) m2[u][r] = -1e30f;
        acc_l[u] = (f32x4){0.f, 0.f, 0.f, 0.f};
        #pragma unroll
        for (int nt = 0; nt < 4; nt++) acc_o[u][nt] = (f32x4){0.f, 0.f, 0.f, 0.f};
    }

    stage(0, 0);
    for (int it = 0; it < 16; it++) {
        int cb = it & 1;
        if (it < 15) {
            stage(cb ^ 1, (it + 1) << 6);
            asm volatile("s_waitcnt vmcnt(4)" ::: "memory");   // cur tile landed
        } else {
            asm volatile("s_waitcnt vmcnt(0)" ::: "memory");
        }
        __builtin_amdgcn_s_barrier();
        asm volatile("" ::: "memory");

        // ---- K frags from LDS (shared by both q-sets)
        bf16x8 kf[4][2];
        #pragma unroll
        for (int j = 0; j < 4; j++)
            #pragma unroll
            for (int s = 0; s < 2; s++)
                kf[j][s] = *(const bf16x8*)&Kls[cb][(16 * j + la) * 64 + (((4 * s + lb) ^ swz) << 3)];

        // ---- S = Q K^T for both q-sets
        f32x4 sj[2][4];
        #pragma unroll
        for (int u = 0; u < 2; u++)
            #pragma unroll
            for (int j = 0; j < 4; j++) sj[u][j] = (f32x4){0.f, 0.f, 0.f, 0.f};
        __builtin_amdgcn_s_setprio(1);
        #pragma unroll
        for (int j = 0; j < 4; j++)
            #pragma unroll
            for (int s = 0; s < 2; s++)
                #pragma unroll
                for (int u = 0; u < 2; u++)
                    sj[u][j] = __builtin_amdgcn_mfma_f32_16x16x32_bf16(av[u][s], kf[j][s], sj[u][j], 0, 0, 0);
        __builtin_amdgcn_s_setprio(0);

        // ---- softmax per q-set: log2 domain, deferred max (round-11 form)
        #pragma unroll
        for (int u = 0; u < 2; u++) {
            float x2[4][4];
            #pragma unroll
            for (int j = 0; j < 4; j++)
                #pragma unroll
                for (int r = 0; r < 4; r++) x2[j][r] = sj[u][j][r] * sc2;

            float p[4][4];
            #pragma unroll
            for (int j = 0; j < 4; j++)
                #pragma unroll
                for (int r = 0; r < 4; r++)
                    p[j][r] = __builtin_amdgcn_exp2f(x2[j][r] - m2[u][r]);

            float mt2[4];
            #pragma unroll
            for (int r = 0; r < 4; r++)
                mt2[r] = fmaxf(fmaxf(x2[0][r], x2[1][r]), fmaxf(x2[2][r], x2[3][r]));
            #pragma unroll
            for (int off = 1; off <= 8; off <<= 1)
                #pragma unroll
                for (int r = 0; r < 4; r++)
                    mt2[r] = fmaxf(mt2[r], __shfl_xor(mt2[r], off, 64));

            int ok = (mt2[0] <= m2[u][0] + 11.f) && (mt2[1] <= m2[u][1] + 11.f) &&
                     (mt2[2] <= m2[u][2] + 11.f) && (mt2[3] <= m2[u][3] + 11.f);
            if (!__all(ok)) {
                #pragma unroll
                for (int r = 0; r < 4; r++) {
                    float mn = fmaxf(m2[u][r], mt2[r]);
                    float al = __builtin_amdgcn_exp2f(m2[u][r] - mn);
                    acc_l[u][r] *= al;
                    #pragma unroll
                    for (int nt = 0; nt < 4; nt++) acc_o[u][nt][r] *= al;
                    m2[u][r] = mn;
                }
                #pragma unroll
                for (int j = 0; j < 4; j++)
                    #pragma unroll
                    for (int r = 0; r < 4; r++)
                        p[j][r] = __builtin_amdgcn_exp2f(x2[j][r] - m2[u][r]);
            }

            // P pack (cvt_pk) -> wave-private LDS rows [u*16, u*16+16)
            #pragma unroll
            for (int j = 0; j < 4; j++)
                #pragma unroll
                for (int rp = 0; rp < 2; rp++) {
                    unsigned uw;
                    asm("v_cvt_pk_bf16_f32 %0, %1, %2"
                        : "=v"(uw) : "v"(p[j][2 * rp]), "v"(p[j][2 * rp + 1]));
                    Ps[w][u * 16 + lb * 4 + 2 * rp][16 * j + la]     = (unsigned short)uw;
                    Ps[w][u * 16 + lb * 4 + 2 * rp + 1][16 * j + la] = (unsigned short)(uw >> 16);
                }
        }
        asm volatile("s_waitcnt lgkmcnt(0)" ::: "memory");
        bf16x8 pf[2][2];
        #pragma unroll
        for (int u = 0; u < 2; u++)
            #pragma unroll
            for (int s = 0; s < 2; s++)
                pf[u][s] = *(const bf16x8*)&Ps[w][u * 16 + la][32 * s + 8 * lb];

        // ---- V frags from LDS (shared), O += P V ; l += P·1
        bf16x8 vf[4][2];
        #pragma unroll
        for (int nt = 0; nt < 4; nt++)
            #pragma unroll
            for (int s = 0; s < 2; s++)
                vf[nt][s] = *(const bf16x8*)&Vls[cb][(16 * nt + la) * 64 + (((4 * s + lb) ^ swz) << 3)];
        __builtin_amdgcn_s_setprio(1);
        #pragma unroll
        for (int nt = 0; nt < 4; nt++)
            #pragma unroll
            for (int s = 0; s < 2; s++)
                #pragma unroll
                for (int u = 0; u < 2; u++)
                    acc_o[u][nt] = __builtin_amdgcn_mfma_f32_16x16x32_bf16(pf[u][s], vf[nt][s], acc_o[u][nt], 0, 0, 0);
        #pragma unroll
        for (int s = 0; s < 2; s++)
            #pragma unroll
            for (int u = 0; u < 2; u++)
                acc_l[u] = __builtin_amdgcn_mfma_f32_16x16x32_bf16(pf[u][s], ones, acc_l[u], 0, 0, 0);
        __builtin_amdgcn_s_setprio(0);

        // drain ds_reads so next iteration's restage of buf cb can't race them
        asm volatile("s_waitcnt lgkmcnt(0)" ::: "memory");
        __builtin_amdgcn_s_barrier();
    }

    // ---- epilogue: O/l, A-swizzled store (K=768 layout)
    #pragma unroll
    for (int u = 0; u < 2; u++) {
        float inv[4];
        #pragma unroll
        for (int r = 0; r < 4; r++) inv[r] = 1.0f / acc_l[u][r];
        size_t mhi = ((size_t)bb * cN + qt0 + u * 16) >> 4;
        #pragma unroll
        for (int nt = 0; nt < 4; nt++) {
            int k = h * cHD + 16 * nt + la;
            size_t base = (mhi * 96 + (k >> 3)) * 128 + (k & 7);
            #pragma unroll
            for (int r = 0; r < 4; r++) {
                unsigned short val = f2bf(acc_o[u][nt][r] * inv[r]);
                O[base + (lb * 4 + r) * 8] = val;
            }
        }
    }
}

// ---------------------------------------------------------------------------
extern "C" void kernel_launch(void* const* d_in, const int* in_sizes, int n_in,
                              void* d_out, int out_size, void* d_ws, size_t ws_size,
                              hipStream_t stream) {
    const float* img_tok  = (const float*)d_in[0];
    const float* evt_tok  = (const float*)d_in[1];
    const float* ln_q1_g  = (const float*)d_in[2];
    const float* ln_q1_b  = (const float*)d_in[3];
    const float* ln_kv1_g = (const float*)d_in[4];
    const float* ln_kv1_b = (const float*)d_in[5];
    const float* ln_q2_g  = (const float*)d_in[6];
    const float* ln_q2_b  = (const float*)d_in[7];
    const float* ln_kv2_g = (const float*)d_in[8];
    const float* ln_kv2_b = (const float*)d_in[9];
    const float* ln_mi_g  = (const float*)d_in[10];
    const float* ln_mi_b  = (const float*)d_in[11];
    const float* ln_me_g  = (const float*)d_in[12];
    const float* ln_me_b  = (const float*)d_in[13];
    const float* si_qkv_w  = (const float*)d_in[14];
    const float* si_qkv_b  = (const float*)d_in[15];
    const float* si_proj_w = (const float*)d_in[16];
    const float* si_proj_b = (const float*)d_in[17];
    const float* se_qkv_w  = (const float*)d_in[18];
    const float* se_qkv_b  = (const float*)d_in[19];
    const float* se_proj_w = (const float*)d_in[20];
    const float* se_proj_b = (const float*)d_in[21];
    const float* xei_q_w = (const float*)d_in[22];
    const float* xei_q_b = (const float*)d_in[23];
    const float* xei_k_w = (const float*)d_in[24];
    const float* xei_k_b = (const float*)d_in[25];
    const float* xei_v_w = (const float*)d_in[26];
    const float* xei_v_b = (const float*)d_in[27];
    const float* xei_p_w = (const float*)d_in[28];
    const float* xei_p_b = (const float*)d_in[29];
    const float* xie_q_w = (const float*)d_in[30];
    const float* xie_q_b = (const float*)d_in[31];
    const float* xie_k_w = (const float*)d_in[32];
    const float* xie_k_b = (const float*)d_in[33];
    const float* xie_v_w = (const float*)d_in[34];
    const float* xie_v_b = (const float*)d_in[35];
    const float* xie_p_w = (const float*)d_in[36];
    const float* xie_p_b = (const float*)d_in[37];
    const float* mi_fc1_w = (const float*)d_in[38];
    const float* mi_fc1_b = (const float*)d_in[39];
    const float* mi_fc2_w = (const float*)d_in[40];
    const float* mi_fc2_b = (const float*)d_in[41];
    const float* me_fc1_w = (const float*)d_in[42];
    const float* me_fc1_b = (const float*)d_in[43];
    const float* me_fc2_w = (const float*)d_in[44];
    const float* me_fc2_b = (const float*)d_in[45];

    const size_t U = (size_t)cBN * cD;               // 3,145,728
    unsigned short* wsb = (unsigned short*)d_ws;
    unsigned short* Wz  = wsb;                       // 18,874,368 elems
    unsigned short* LNo = wsb + 18874368;            // U
    unsigned short* AO  = LNo + U;                   // U
    unsigned short* T1  = AO + U;                    // 3U (row stride 2304)
    unsigned short* Vt  = T1 + 3 * U;                // U  [48][64][1024]
    // extended region (batched path only): second QKV set + second hidden
    unsigned short* T1b  = Vt + U;                   // 3U
    unsigned short* Vtb  = T1b + 3 * U;              // U
    unsigned short* Hidb = Vtb + U;                  // 4U
    float* out_img = (float*)d_out;
    float* out_evt = out_img + U;

    const bool big = ws_size >= (size_t)(18874368 + 14 * U) * 2;

    // weight offsets (bf16 elems); 768x768 = 589824
    const size_t O_SI_QKV = 0,        O_SE_QKV = 1769472;
    const size_t O_SI_P   = 3538944,  O_SE_P   = 4128768;
    const size_t O_XEI_Q  = 4718592,  O_XEI_KV = 5308416, O_XEI_P = 6488064;
    const size_t O_XIE_Q  = 7077888,  O_XIE_KV = 7667712, O_XIE_P = 8847360;
    const size_t O_MI_F1  = 9437184,  O_MI_F2  = 11796480;
    const size_t O_ME_F1  = 14155776, O_ME_F2  = 16515072;

    // ---- batched weight conversion (one launch)
    {
        WcTab tab;
        const float* srcs[16] = { si_qkv_w, se_qkv_w, si_proj_w, se_proj_w,
                                  xei_q_w, xei_k_w, xei_v_w, xei_p_w,
                                  xie_q_w, xie_k_w, xie_v_w, xie_p_w,
                                  mi_fc1_w, mi_fc2_w, me_fc1_w, me_fc2_w };
        const size_t offs[16] = { O_SI_QKV, O_SE_QKV, O_SI_P, O_SE_P,
                                  O_XEI_Q, O_XEI_KV, O_XEI_KV + 589824, O_XEI_P,
                                  O_XIE_Q, O_XIE_KV, O_XIE_KV + 589824, O_XIE_P,
                                  O_MI_F1, O_MI_F2, O_ME_F1, O_ME_F2 };
        const int Ks[16] = { 768, 768, 768, 768, 768, 768, 768, 768,
                             768, 768, 768, 768, 768, 3072, 768, 3072 };
        const int Ns[16] = { 2304, 2304, 768, 768, 768, 768, 768, 768,
                             768, 768, 768, 768, 3072, 768, 3072, 768 };
        int acc = 0;
        for (int i = 0; i < 16; i++) {
            tab.src[i] = srcs[i];
            tab.dstoff[i] = offs[i];
            tab.K[i] = Ks[i];
            tab.N[i] = Ns[i];
            tab.start[i] = acc;
            acc += (Ks[i] / 64) * (Ns[i] / 64);
        }
        tab.start[16] = acc;   // 4608
        hipLaunchKernelGGL(wconv_all, dim3(acc), dim3(256), 0, stream, tab, Wz);
    }

    const float SC = 0.125f;

    // helpers ---------------------------------------------------------------
    auto lnN = [&](int nsets, const float* x0, const float* g0, const float* b0, unsigned short* y0,
                   const float* x1, const float* g1, const float* b1, unsigned short* y1,
                   const float* x2, const float* g2, const float* b2, unsigned short* y2,
                   const float* x3, const float* g3, const float* b3, unsigned short* y3) {
        LnTab T = {{x0, x1, x2, x3}, {g0, g1, g2, g3}, {b0, b1, b2, b3}, {y0, y1, y2, y3}};
        hipLaunchKernelGGL(ln4_kernel, dim3(nsets * 256), dim3(256), 0, stream, T);
    };
    auto gemm2 = [&](dim3 grid, GPair P, int K_, int N_, int ostride_, int vsplit_, int mode_) {
        hipLaunchKernelGGL(mfma_gemm, grid, dim3(256), 0, stream, P, K_, N_, ostride_, vsplit_, mode_);
    };
    auto attn2 = [&](int nz, const unsigned short* q0, const unsigned short* k0, const unsigned short* v0, unsigned short* o0,
                     const unsigned short* q1, const unsigned short* k1, const unsigned short* v1, unsigned short* o1,
                     float sc) {
        hipLaunchKernelGGL(fattn_kernel, dim3(cB * cH * 8, 1, nz), dim3(256), 0, stream,
                           q0, q1, k0, k1, v0, v1, o0, o1, 2304, sc);
    };

    if (big) {
        // ================= batched pair schedule =================
        // 1) LN(q1 img)->LNo, LN(kv1 evt)->AO
        lnN(2, img_tok, ln_q1_g, ln_q1_b, LNo,  evt_tok, ln_kv1_g, ln_kv1_b, AO,
               img_tok, ln_q1_g, ln_q1_b, LNo,  img_tok, ln_q1_g, ln_q1_b, LNo);
        // 2) qkv pair: si->T1/Vt, se->T1b/Vtb
        gemm2(dim3(32, 36, 2),
              {LNo, AO, Wz + O_SI_QKV, Wz + O_SE_QKV, si_qkv_b, se_qkv_b,
               si_qkv_b + 1536, se_qkv_b + 1536, nullptr, nullptr, T1, T1b, Vt, Vtb},
              768, 2304, 2304, 1536, 3);
        // 3) attn pair: si->LNo, se->AO
        attn2(2, T1, T1 + 768, Vt, LNo,  T1b, T1b + 768, Vtb, AO, SC);
        // 4) proj pair -> out_img/out_evt (i1/e1)
        gemm2(dim3(32, 12, 2),
              {LNo, AO, Wz + O_SI_P, Wz + O_SE_P, si_proj_b, se_proj_b,
               nullptr, nullptr, img_tok, evt_tok, out_img, out_evt, nullptr, nullptr},
              768, 768, 768, 0, 2);
        // 5) 4 cross LNs: q2(i1)->LNo, kv2(e1)->AO, kv2(i1)->Hidb0, q2(e1)->Hidb1
        lnN(4, out_img, ln_q2_g, ln_q2_b, LNo,   out_evt, ln_kv2_g, ln_kv2_b, AO,
               out_img, ln_kv2_g, ln_kv2_b, Hidb, out_evt, ln_q2_g, ln_q2_b, Hidb + U);
        // 6) q pair: xei_q(LNo)->T1, xie_q(Hidb1)->T1b
        gemm2(dim3(32, 12, 2),
              {LNo, Hidb + U, Wz + O_XEI_Q, Wz + O_XIE_Q, xei_q_b, xie_q_b,
               nullptr, nullptr, nullptr, nullptr, T1, T1b, nullptr, nullptr},
              768, 768, 2304, 1 << 30, 0);
        // 7) kv pair: xei_kv(AO)->T1+768/Vt, xie_kv(Hidb0)->T1b+768/Vtb
        gemm2(dim3(32, 24, 2),
              {AO, Hidb, Wz + O_XEI_KV, Wz + O_XIE_KV, xei_k_b, xie_k_b,
               xei_v_b, xie_v_b, nullptr, nullptr, T1 + 768, T1b + 768, Vt, Vtb},
              768, 1536, 2304, 768, 3);
        // 8) attn pair (negated): xei->LNo, xie->AO
        attn2(2, T1, T1 + 768, Vt, LNo,  T1b, T1b + 768, Vtb, AO, -SC);
        // 9) P pair -> i2/e2
        gemm2(dim3(32, 12, 2),
              {LNo, AO, Wz + O_XEI_P, Wz + O_XIE_P, xei_p_b, xie_p_b,
               nullptr, nullptr, out_img, out_evt, out_img, out_evt, nullptr, nullptr},
              768, 768, 768, 0, 2);
        // 10) MLP LNs: mi->LNo, me->AO
        lnN(2, out_img, ln_mi_g, ln_mi_b, LNo,  out_evt, ln_me_g, ln_me_b, AO,
               out_img, ln_mi_g, ln_mi_b, LNo,  out_img, ln_mi_g, ln_mi_b, LNo);
        // 11) fc1 pair: mi->Hid_mi(=T1..Vt 4U), me->Hidb
        gemm2(dim3(32, 48, 2),
              {LNo, AO, Wz + O_MI_F1, Wz + O_ME_F1, mi_fc1_b, me_fc1_b,
               nullptr, nullptr, nullptr, nullptr, T1, Hidb, nullptr, nullptr},
              768, 3072, 3072, 0, 1);
        // 12) fc2 pair -> final outputs
        gemm2(dim3(32, 12, 2),
              {T1, Hidb, Wz + O_MI_F2, Wz + O_ME_F2, mi_fc2_b, me_fc2_b,
               nullptr, nullptr, out_img, out_evt, out_img, out_evt, nullptr, nullptr},
              3072, 768, 768, 0, 2);
    } else {
        // ================= fallback: round-4 sequential schedule =================
        unsigned short* Hid = AO;   // 4U alias (AO + T1)
        auto ln1 = [&](const float* x_, const float* g_, const float* b_, unsigned short* y_) {
            lnN(1, x_, g_, b_, y_, x_, g_, b_, y_, x_, g_, b_, y_, x_, g_, b_, y_);
        };
        auto gemm1 = [&](const unsigned short* A_, size_t woff, const float* b_, const float* bB_,
                         const float* r_, void* C_, unsigned short* V_, int K_, int N_,
                         int ostride_, int vsplit_, int mode_) {
            gemm2(dim3(cBN / 128, N_ / 64, 1),
                  {A_, A_, Wz + woff, Wz + woff, b_, b_, bB_, bB_, r_, r_, C_, C_, V_, V_},
                  K_, N_, ostride_, vsplit_, mode_);
        };
        auto attn1 = [&](const unsigned short* q_, const unsigned short* k_,
                         unsigned short* o_, float sc_) {
            attn2(1, q_, k_, Vt, o_, q_, k_, Vt, o_, sc_);
        };

        ln1(img_tok, ln_q1_g, ln_q1_b, LNo);
        gemm1(LNo, O_SI_QKV, si_qkv_b, si_qkv_b + 1536, nullptr, T1, Vt, 768, 2304, 2304, 1536, 3);
        attn1(T1, T1 + 768, AO, SC);
        gemm1(AO, O_SI_P, si_proj_b, nullptr, img_tok, out_img, Vt, 768, 768, 768, 0, 2);

        ln1(evt_tok, ln_kv1_g, ln_kv1_b, LNo);
        gemm1(LNo, O_SE_QKV, se_qkv_b, se_qkv_b + 1536, nullptr, T1, Vt, 768, 2304, 2304, 1536, 3);
        attn1(T1, T1 + 768, AO, SC);
        gemm1(AO, O_SE_P, se_proj_b, nullptr, evt_tok, out_evt, Vt, 768, 768, 768, 0, 2);

        ln1(out_img, ln_q2_g, ln_q2_b, LNo);
        gemm1(LNo, O_XEI_Q, xei_q_b, nullptr, nullptr, T1, Vt, 768, 768, 2304, 1 << 30, 0);
        ln1(out_evt, ln_kv2_g, ln_kv2_b, LNo);
        gemm1(LNo, O_XEI_KV, xei_k_b, xei_v_b, nullptr, T1 + 768, Vt, 768, 1536, 2304, 768, 3);
        attn1(T1, T1 + 768, AO, -SC);

        ln1(out_img, ln_kv2_g, ln_kv2_b, LNo);
        gemm1(LNo, O_XIE_KV, xie_k_b, xie_v_b, nullptr, T1 + 768, Vt, 768, 1536, 2304, 768, 3);
        ln1(out_evt, ln_q2_g, ln_q2_b, LNo);
        gemm1(LNo, O_XIE_Q, xie_q_b, nullptr, nullptr, T1, Vt, 768, 768, 2304, 1 << 30, 0);

        gemm1(AO, O_XEI_P, xei_p_b, nullptr, out_img, out_img, Vt, 768, 768, 768, 0, 2);
        attn1(T1, T1 + 768, AO, -SC);
        gemm1(AO, O_XIE_P, xie_p_b, nullptr, out_evt, out_evt, Vt, 768, 768, 768, 0, 2);

        lnN(2, out_img, ln_mi_g, ln_mi_b, LNo,  out_evt, ln_me_g, ln_me_b, Vt,
               out_img, ln_mi_g, ln_mi_b, LNo,  out_img, ln_mi_g, ln_mi_b, LNo);
        gemm1(LNo, O_MI_F1, mi_fc1_b, nullptr, nullptr, Hid, Vt, 768, 3072, 3072, 0, 1);
        gemm1(Hid, O_MI_F2, mi_fc2_b, nullptr, out_img, out_img, Vt, 3072, 768, 768, 0, 2);
        gemm1(Vt,  O_ME_F1, me_fc1_b, nullptr, nullptr, Hid, Vt, 768, 3072, 3072, 0, 1);
        gemm1(Hid, O_ME_F2, me_fc2_b, nullptr, out_evt, out_evt, Vt, 3072, 768, 768, 0, 2);
    }
}